// Round 1
// baseline (187.082 us; speedup 1.0000x reference)
//
#include <hip/hip_runtime.h>
#include <math.h>

// Problem constants (from setup_inputs): B=16, T=8192, N=32, depth=31, 5 ops.
constexpr int N_STACK = 32;
constexpr int DEPTH = 31;
constexpr int NOPS = 5;
constexpr int BLOCK = 256;

#define LOG_LIMF 10.0f

// Exact 1/(32-k) constants, bit-identical to the compile-time-folded values
// the fully-unrolled version used (rolled loop would otherwise emit a runtime
// divide / rcp with different rounding).
__device__ __constant__ float INV_CS_TBL[DEPTH] = {
    1.0f/32.0f, 1.0f/31.0f, 1.0f/30.0f, 1.0f/29.0f, 1.0f/28.0f, 1.0f/27.0f,
    1.0f/26.0f, 1.0f/25.0f, 1.0f/24.0f, 1.0f/23.0f, 1.0f/22.0f, 1.0f/21.0f,
    1.0f/20.0f, 1.0f/19.0f, 1.0f/18.0f, 1.0f/17.0f, 1.0f/16.0f, 1.0f/15.0f,
    1.0f/14.0f, 1.0f/13.0f, 1.0f/12.0f, 1.0f/11.0f, 1.0f/10.0f, 1.0f/9.0f,
    1.0f/8.0f,  1.0f/7.0f,  1.0f/6.0f,  1.0f/5.0f,  1.0f/4.0f,  1.0f/3.0f,
    1.0f/2.0f
};

// _clip_log(l) = tanh(l/10)*10, via tanh(x) = (e^{2x}-1)/(e^{2x}+1)
__device__ __forceinline__ float clip_log(float l) {
    float tx = 0.2f * l;                       // 2*(l/10)
    tx = fminf(fmaxf(tx, -80.0f), 80.0f);      // keep exp finite
    float t = __expf(tx);
    return 10.0f * (t - 1.0f) * __builtin_amdgcn_rcpf(t + 1.0f);
}

// add_log_space branch combine. Shared numeric pieces (l_same_c, nlog, zres, bx)
// are computed once outside (they do not depend on signs). sy is +acc for add,
// -acc for sub.
__device__ __forceinline__ void add_ls(float sx, float lx, float sy, float ly,
                                       float l_same_c, float nlog, bool zres, bool bx,
                                       float &s_o, float &l_o)
{
    bool zx = (sx == 0.0f);
    bool zy = (sy == 0.0f);
    bool both = (!zx) && (!zy);
    bool same_sign = (sx * sy > 0.0f);
    bool same_br = both && same_sign;
    bool opp_br  = both && !same_sign;

    float s = 0.0f, l = 0.0f;          // default: both zero
    if ((!zx) && zy) { s = sx; l = lx; }
    if (zx && (!zy)) { s = sy; l = ly; }
    if (same_br) { s = (sx > 0.0f) ? 1.0f : -1.0f; l = l_same_c; }
    if (opp_br)  { s = zres ? 0.0f : (bx ? sx : sy); l = nlog; }
    s_o = s;
    l_o = clip_log(l);                 // reference clips l_out on return
}

// Grid is hard-capped at 2 waves/SIMD (131072 thr = 2048 waves on 1024 SIMDs).
// LDS (64KB/WG) caps residency at the same 2 WG/CU, so nothing is lost.
//
// KEY CHANGE vs previous version: the depth loop is ROLLED. The fully-unrolled
// body was ~35-40KB of straight-line code executed once per wave -> permanent
// L1I streaming from L2 (the unexplained ~70% stall: VALUBusy 29%, HBM 18%,
// zero LDS conflicts). Rolled body is ~2-3KB and stays icache-resident.
// Stack lives in LDS (one column per thread, no __syncthreads needed);
// ops stream through a 2-deep register pipeline.
__global__ __launch_bounds__(BLOCK)
__attribute__((amdgpu_waves_per_eu(2, 2)))
void stack_fold_kernel(const float* __restrict__ sgn,
                       const float* __restrict__ logm,
                       const float* __restrict__ ops,
                       float* __restrict__ out, int n)
{
    // (stack index i, tid) -> (s, l). 32*256*8B = 64 KiB.
    // Addr for lane t at index i: i*2048 + t*8 -> contiguous 8B/lane,
    // conflict-free ds_read_b64 / ds_write_b64.
    __shared__ float2 st[N_STACK * BLOCK];

    const int tid = threadIdx.x;
    const int id = blockIdx.x * BLOCK + tid;
    if (id >= n) return;

    // Per-thread contiguous slices; id*128 bytes => float4 aligned.
    const float4* sg4 = reinterpret_cast<const float4*>(sgn  + (size_t)id * N_STACK);
    const float4* lg4 = reinterpret_cast<const float4*>(logm + (size_t)id * N_STACK);
    const float* op = ops + (size_t)id * (DEPTH * NOPS);

    // ---- stage stack to LDS, build suffix sum-of-squares S over logs 0..30 ----
    // (same fmaf accumulation order as the unrolled version: 0,1,2,...,30)
    float S = 0.0f;
    float4 a7, b7;
#pragma unroll
    for (int i = 0; i < N_STACK / 4; ++i) {
        float4 a = sg4[i];
        float4 b = lg4[i];
        st[(4*i+0)*BLOCK + tid] = make_float2(a.x, b.x);
        st[(4*i+1)*BLOCK + tid] = make_float2(a.y, b.y);
        st[(4*i+2)*BLOCK + tid] = make_float2(a.z, b.z);
        st[(4*i+3)*BLOCK + tid] = make_float2(a.w, b.w);
        S = fmaf(b.x, b.x, S);
        S = fmaf(b.y, b.y, S);
        S = fmaf(b.z, b.z, S);
        if (i < 7) S = fmaf(b.w, b.w, S);   // exclude top element (index 31)
        if (i == 7) { a7 = a; b7 = b; }
    }

    // Accumulator = top of stack (index 31); step-0 operand = index 30.
    float as_ = a7.w, al = b7.w;
    float ss_c = a7.z, sl_c = b7.z;

    // 2-deep op-probability pipeline: pa = row k, pb = row k+1.
    float pa0 = op[0], pa1 = op[1], pa2 = op[2], pa3 = op[3], pa4 = op[4];
    float pb0 = op[5], pb1 = op[6], pb2 = op[7], pb3 = op[8], pb4 = op[9];

#pragma unroll 2
    for (int k = 0; k < DEPTH; ++k) {
        // ---- prefetch: stack element for step k+1 (LDS, distance 1),
        //      op row k+2 (global, distance 2). Clamped indices: redundant
        //      harmless loads on the last iterations, values never consumed.
        int i1 = 29 - k; i1 = (i1 < 0) ? 0 : i1;
        float2 nx = st[i1 * BLOCK + tid];
        int r2 = k + 2; r2 = (r2 > DEPTH - 1) ? (DEPTH - 1) : r2;
        const float* o2 = op + r2 * NOPS;
        float pc0 = o2[0], pc1 = o2[1], pc2 = o2[2], pc3 = o2[3], pc4 = o2[4];

        float ss = ss_c, sl = sl_c;
        float p0 = pa0, p1 = pa1, p2 = pa2, p3 = pa3, p4 = pa4;

        // ---- shared add/sub numeric core (sign-independent) ----
        float d = sl - al;
        float mx = fmaxf(sl, al);
        float lse = mx + __logf(1.0f + __expf(-fabsf(d)));   // logaddexp
        float l_same_c = clip_log(lse);

        bool bx = (sl >= al);                 // bigger_is_x
        float big    = bx ? sl : al;
        float small_ = bx ? al : sl;
        float delta = fminf(fmaxf(small_ - big, -LOG_LIMF), -0.001f);
        float diff = __logf(1.0f - __expf(delta));           // log1p(-exp(delta))
        bool zres = (small_ == big);
        float nlog = zres ? 0.0f : (big + diff);

        // ---- add / sub branch combines ----
        float s_add, l_add, s_sub, l_sub;
        add_ls(ss, sl,  as_, al, l_same_c, nlog, zres, bx, s_add, l_add);
        add_ls(ss, sl, -as_, al, l_same_c, nlog, zres, bx, s_sub, l_sub);

        // ---- mul / div ----
        float sm   = ss * as_;
        float lmul = clip_log(sl + al);
        float ldiv = clip_log(sl - al);

        // ---- soft mix over [add, sub, mul, div, identity(sec)] ----
        float rs = p0 * s_add + p1 * s_sub + (p2 + p3) * sm + p4 * ss;
        float rl = p0 * l_add + p1 * l_sub + p2 * lmul + p3 * ldiv + p4 * sl;

        // ---- RMS rescale: slice = original logs 0..30-k ++ rl (cs = 32-k)
        float inv_cs = INV_CS_TBL[k];        // exact compile-time constant
        float ms = fmaf(rl, rl, S) * inv_cs + 1e-6f;
        float scale = fminf(10.0f * __builtin_amdgcn_rsqf(ms), 1.0f);
        rl = rl * scale;

        // retire original element 30-k from the suffix sum
        S = fmaf(-sl, sl, S);

        as_ = rs;
        al  = rl;

        // ---- rotate software pipeline ----
        ss_c = nx.x; sl_c = nx.y;
        pa0 = pb0; pa1 = pb1; pa2 = pb2; pa3 = pb3; pa4 = pb4;
        pb0 = pc0; pb1 = pc1; pb2 = pc2; pb3 = pc3; pb4 = pc4;
    }

    // Output: (2, B, T) flattened — [0..n) = sign, [n..2n) = log
    out[id]     = as_;
    out[n + id] = al;
}

extern "C" void kernel_launch(void* const* d_in, const int* in_sizes, int n_in,
                              void* d_out, int out_size, void* d_ws, size_t ws_size,
                              hipStream_t stream) {
    const float* sgn  = (const float*)d_in[0];
    const float* logm = (const float*)d_in[1];
    const float* ops  = (const float*)d_in[2];
    float* out = (float*)d_out;

    int n = in_sizes[0] / N_STACK;   // B*T = 131072
    int blocks = (n + BLOCK - 1) / BLOCK;
    stack_fold_kernel<<<blocks, BLOCK, 0, stream>>>(sgn, logm, ops, out, n);
}

// Round 2
// 157.935 us; speedup vs baseline: 1.1846x; 1.1846x over previous
//
#include <hip/hip_runtime.h>
#include <math.h>

// Problem constants (from setup_inputs): B=16, T=8192, N=32, depth=31, 5 ops.
constexpr int N_STACK = 32;
constexpr int DEPTH = 31;
constexpr int NOPS = 5;
constexpr int BLOCK = 256;
constexpr int CH = 8;                      // steps per chunk
constexpr int NCH = (DEPTH + CH - 1) / CH; // 4 chunks: 8,8,8,7 steps
constexpr int ROWPAD = 41;                 // 40-dword chunk rows padded to 41:
                                           // read bank = (9*lane + w) % 32 -> conflict-free
constexpr int WAVE_LDS = 64 * ROWPAD;      // dwords of LDS per wave

#define LOG_LIMF 10.0f

// Force x to be materialized in a VGPR here (s_waitcnt lands here, and the
// producing load cannot be re-sunk to the use site).
#define PIN(x) asm volatile("" : "+v"(x))

// _clip_log(l) = tanh(l/10)*10, via tanh(x) = (e^{2x}-1)/(e^{2x}+1)
__device__ __forceinline__ float clip_log(float l) {
    float tx = 0.2f * l;                       // 2*(l/10)
    tx = fminf(fmaxf(tx, -80.0f), 80.0f);      // keep exp finite
    float t = __expf(tx);
    return 10.0f * (t - 1.0f) * __builtin_amdgcn_rcpf(t + 1.0f);
}

// add_log_space branch combine. Shared numeric pieces (l_same_c, nlog, zres, bx)
// are computed once outside (they do not depend on signs). sy is +acc for add,
// -acc for sub.
__device__ __forceinline__ void add_ls(float sx, float lx, float sy, float ly,
                                       float l_same_c, float nlog, bool zres, bool bx,
                                       float &s_o, float &l_o)
{
    bool zx = (sx == 0.0f);
    bool zy = (sy == 0.0f);
    bool both = (!zx) && (!zy);
    bool same_sign = (sx * sy > 0.0f);
    bool same_br = both && same_sign;
    bool opp_br  = both && !same_sign;

    float s = 0.0f, l = 0.0f;          // default: both zero
    if ((!zx) && zy) { s = sx; l = lx; }
    if (zx && (!zy)) { s = sy; l = ly; }
    if (same_br) { s = (sx > 0.0f) ? 1.0f : -1.0f; l = l_same_c; }
    if (opp_br)  { s = zres ? 0.0f : (bx ? sx : sy); l = nlog; }
    s_o = s;
    l_o = clip_log(l);                 // reference clips l_out on return
}

// Grid hard-caps occupancy at 2 waves/SIMD (131072 thr = 2048 waves on 1024
// SIMDs). Structure = the proven unrolled kernel; ONE change vs the 49.6us
// version: op-probability loads are now WAVE-COALESCED.
//
// Why: rocprof showed VALUBusy 29%, HBM 18%, LDS-conflicts 0 at 49.6us/disp.
// The serialized resource is the L1 texture addresser: per-thread op loads put
// 64 lanes on 64 distinct cache lines per instruction (stride 620B). 8 waves
// x 171 loads x 64 lines ~= 87k line-transactions/CU ~= the 119k-cycle wall.
// A wave's 64 op rows are CONTIGUOUS (64 x 620B), so each 8-step chunk
// (64 rows x 160B) is loaded flat-coalesced (~5 lines/instr) into registers,
// transposed through a per-wave LDS buffer (rows padded to 41 dwords), and
// the 5 per-step probs are read from LDS (bank-conflict-free, 2-way max).
__global__ __launch_bounds__(BLOCK)
__attribute__((amdgpu_waves_per_eu(2, 2)))
void stack_fold_kernel(const float* __restrict__ sgn,
                       const float* __restrict__ logm,
                       const float* __restrict__ ops,
                       float* __restrict__ out, int n)
{
    __shared__ float lops[4 * WAVE_LDS];   // 4 waves x 64 rows x 41 dwords = 41,984B

    const int tid  = threadIdx.x;
    const int id   = blockIdx.x * BLOCK + tid;
    if (id >= n) return;
    const int lane = tid & 63;
    const int wid  = tid >> 6;
    float* wl = lops + wid * WAVE_LDS;

    // Per-thread contiguous slices; id*128 bytes => float4 aligned.
    const float4* sg4 = reinterpret_cast<const float4*>(sgn  + (size_t)id * N_STACK);
    const float4* lg4 = reinterpret_cast<const float4*>(logm + (size_t)id * N_STACK);
    // Wave's op region: 64 contiguous rows of 155 floats.
    const float* wop = ops + (size_t)(blockIdx.x * BLOCK + wid * 64) * (DEPTH * NOPS);

    // ---- issue chunk-0 coalesced loads (64 rows x 40 words, flat u-order) ----
    // u = i*64+lane; row r = u/40, word w = u%40; addr = r*155 + w = u + 115*r.
    float c0[40];
#pragma unroll
    for (int i = 0; i < 40; ++i) {
        int u = i * 64 + lane;
        int r = u / 40;
        c0[i] = wop[u + 115 * r];
    }

    // ---- stack loads (per-thread float4; only 16 instrs, minor TA cost) ----
    float s_arr[N_STACK], l_arr[N_STACK];
#pragma unroll
    for (int i = 0; i < N_STACK / 4; ++i) {
        float4 a = sg4[i];
        float4 b = lg4[i];
        s_arr[4*i+0] = a.x; s_arr[4*i+1] = a.y; s_arr[4*i+2] = a.z; s_arr[4*i+3] = a.w;
        l_arr[4*i+0] = b.x; l_arr[4*i+1] = b.y; l_arr[4*i+2] = b.z; l_arr[4*i+3] = b.w;
    }
#pragma unroll
    for (int i = 0; i < N_STACK; ++i) { PIN(s_arr[i]); PIN(l_arr[i]); }

    // Suffix sum-of-squares of ORIGINAL logs, positions 0..30 (top excluded).
    float S = 0.0f;
#pragma unroll
    for (int i = 0; i < N_STACK - 1; ++i) S = fmaf(l_arr[i], l_arr[i], S);

    // Accumulator = top of stack.
    float as_ = s_arr[N_STACK - 1];
    float al  = l_arr[N_STACK - 1];

    // ---- chunk-0 into LDS (write addr = 41*r + w = u + r) ----
#pragma unroll
    for (int i = 0; i < 40; ++i) PIN(c0[i]);
#pragma unroll
    for (int i = 0; i < 40; ++i) {
        int u = i * 64 + lane;
        int r = u / 40;
        wl[u + r] = c0[i];
    }

    const int roff = lane * ROWPAD;

#pragma unroll
    for (int c = 0; c < NCH; ++c) {
        // ---- issue coalesced loads for chunk c+1 NOW (complete under compute) ----
        float nxt[40];
        const int Wn = (c + 1 == 3) ? 35 : 40;   // last chunk: 7 steps = 35 words
        if (c + 1 < NCH) {
#pragma unroll
            for (int i = 0; i < Wn; ++i) {
                int u = i * 64 + lane;
                int r = u / Wn;                   // constexpr divisor (magic mul)
                nxt[i] = wop[u + (155 - Wn) * r + (c + 1) * 40];
            }
        }

#pragma unroll
        for (int j = 0; j < CH; ++j) {
            const int k = c * CH + j;
            if (k < DEPTH) {
                float ss = s_arr[N_STACK - 2 - k];   // sec (original input)
                float sl = l_arr[N_STACK - 2 - k];

                // per-step probs from this wave's LDS slice (conflict-free)
                float p0 = wl[roff + j * NOPS + 0];
                float p1 = wl[roff + j * NOPS + 1];
                float p2 = wl[roff + j * NOPS + 2];
                float p3 = wl[roff + j * NOPS + 3];
                float p4 = wl[roff + j * NOPS + 4];

                // ---- shared add/sub numeric core (sign-independent) ----
                float d = sl - al;
                float mx = fmaxf(sl, al);
                float lse = mx + __logf(1.0f + __expf(-fabsf(d)));   // logaddexp
                float l_same_c = clip_log(lse);

                bool bx = (sl >= al);                 // bigger_is_x
                float big    = bx ? sl : al;
                float small_ = bx ? al : sl;
                float delta = fminf(fmaxf(small_ - big, -LOG_LIMF), -0.001f);
                float diff = __logf(1.0f - __expf(delta));           // log1p(-exp(delta))
                bool zres = (small_ == big);
                float nlog = zres ? 0.0f : (big + diff);

                // ---- add / sub branch combines ----
                float s_add, l_add, s_sub, l_sub;
                add_ls(ss, sl,  as_, al, l_same_c, nlog, zres, bx, s_add, l_add);
                add_ls(ss, sl, -as_, al, l_same_c, nlog, zres, bx, s_sub, l_sub);

                // ---- mul / div ----
                float sm   = ss * as_;
                float lmul = clip_log(sl + al);
                float ldiv = clip_log(sl - al);

                // ---- soft mix over [add, sub, mul, div, identity(sec)] ----
                float rs = p0 * s_add + p1 * s_sub + (p2 + p3) * sm + p4 * ss;
                float rl = p0 * l_add + p1 * l_sub + p2 * lmul + p3 * ldiv + p4 * sl;

                // ---- RMS rescale: slice = original logs 0..30-k ++ rl (cs = 32-k)
                const float inv_cs = 1.0f / (float)(N_STACK - k);    // compile-time
                float ms = fmaf(rl, rl, S) * inv_cs + 1e-6f;
                float scale = fminf(10.0f * __builtin_amdgcn_rsqf(ms), 1.0f);
                rl = rl * scale;

                // retire original element 30-k from the suffix sum
                S = fmaf(-sl, sl, S);

                as_ = rs;
                al  = rl;
            }
        }

        // ---- chunk c+1 regs -> LDS (waitcnt lands here, behind ~8 steps of ALU;
        //      single buffer is safe: all chunk-c LDS reads precede these writes
        //      in wave-synchronous program order) ----
        if (c + 1 < NCH) {
#pragma unroll
            for (int i = 0; i < Wn; ++i) PIN(nxt[i]);
#pragma unroll
            for (int i = 0; i < Wn; ++i) {
                int u = i * 64 + lane;
                int r = u / Wn;
                wl[u + (ROWPAD - Wn) * r] = nxt[i];
            }
        }
    }

    // Output: (2, B, T) flattened — [0..n) = sign, [n..2n) = log
    out[id]     = as_;
    out[n + id] = al;
}

extern "C" void kernel_launch(void* const* d_in, const int* in_sizes, int n_in,
                              void* d_out, int out_size, void* d_ws, size_t ws_size,
                              hipStream_t stream) {
    const float* sgn  = (const float*)d_in[0];
    const float* logm = (const float*)d_in[1];
    const float* ops  = (const float*)d_in[2];
    float* out = (float*)d_out;

    int n = in_sizes[0] / N_STACK;   // B*T = 131072
    int blocks = (n + BLOCK - 1) / BLOCK;
    stack_fold_kernel<<<blocks, BLOCK, 0, stream>>>(sgn, logm, ops, out, n);
}

// Round 3
// 153.575 us; speedup vs baseline: 1.2182x; 1.0284x over previous
//
#include <hip/hip_runtime.h>
#include <math.h>

// Problem constants (from setup_inputs): B=16, T=8192, N=32, depth=31, 5 ops.
constexpr int N_STACK = 32;
constexpr int DEPTH = 31;
constexpr int NOPS = 5;
constexpr int BLOCK = 256;
constexpr int CH = 8;                      // steps per prefetch chunk
constexpr int NCH = (DEPTH + CH - 1) / CH; // 4 chunks: 8,8,8,7

#define LOG_LIMF 10.0f

// Force x to be materialized in a VGPR here; the result is opaque, so the
// compiler cannot re-sink / rematerialize the producing load at the use site.
#define PIN(x) asm volatile("" : "+v"(x))

// Dword-aligned float4: op rows are 155 floats (620B) so thread bases are only
// 4B-aligned. gfx950 unaligned-access mode handles dwordx4 @ 4B alignment; if
// the compiler chooses to split, we degrade exactly to the proven scalar form.
typedef float f4v __attribute__((ext_vector_type(4), aligned(4)));

// _clip_log(l) = tanh(l/10)*10, via tanh(x) = (e^{2x}-1)/(e^{2x}+1)
__device__ __forceinline__ float clip_log(float l) {
    float tx = 0.2f * l;                       // 2*(l/10)
    tx = fminf(fmaxf(tx, -80.0f), 80.0f);      // keep exp finite
    float t = __expf(tx);
    return 10.0f * (t - 1.0f) * __builtin_amdgcn_rcpf(t + 1.0f);
}

// add_log_space branch combine. Shared numeric pieces (l_same_c, nlog, zres, bx)
// are computed once outside (they do not depend on signs). sy is +acc for add,
// -acc for sub.
__device__ __forceinline__ void add_ls(float sx, float lx, float sy, float ly,
                                       float l_same_c, float nlog, bool zres, bool bx,
                                       float &s_o, float &l_o)
{
    bool zx = (sx == 0.0f);
    bool zy = (sy == 0.0f);
    bool both = (!zx) && (!zy);
    bool same_sign = (sx * sy > 0.0f);
    bool same_br = both && same_sign;
    bool opp_br  = both && !same_sign;

    float s = 0.0f, l = 0.0f;          // default: both zero
    if ((!zx) && zy) { s = sx; l = lx; }
    if (zx && (!zy)) { s = sy; l = ly; }
    if (same_br) { s = (sx > 0.0f) ? 1.0f : -1.0f; l = l_same_c; }
    if (opp_br)  { s = zres ? 0.0f : (bx ? sx : sy); l = nlog; }
    s_o = s;
    l_o = clip_log(l);                 // reference clips l_out on return
}

// Grid is hard-capped at 2 waves/SIMD (131072 thr = 2048 waves on 1024 SIMDs).
// Structure identical to the proven 49.6us/dispatch kernel. ONE change:
// per-chunk op loads are 10 x dwordx4 instead of 40 x dword (4x fewer
// divergent load instructions through the TA). Minimal isolating experiment
// for the "memory-front-end line-lookup serialization" theory; R2's LDS
// transpose bundled too many confounds to read.
__global__ __launch_bounds__(BLOCK)
__attribute__((amdgpu_waves_per_eu(2, 2)))
void stack_fold_kernel(const float* __restrict__ sgn,
                       const float* __restrict__ logm,
                       const float* __restrict__ ops,
                       float* __restrict__ out, int n)
{
    int id = blockIdx.x * BLOCK + threadIdx.x;
    if (id >= n) return;

    // Per-thread contiguous slices; id*128 bytes => float4 aligned.
    const float4* sg4 = reinterpret_cast<const float4*>(sgn  + (size_t)id * N_STACK);
    const float4* lg4 = reinterpret_cast<const float4*>(logm + (size_t)id * N_STACK);
    const float* op = ops + (size_t)id * (DEPTH * NOPS);

    // ---- issue ALL stack loads + chunk-0 ops loads, then pin ----
    float s_arr[N_STACK], l_arr[N_STACK];
#pragma unroll
    for (int i = 0; i < N_STACK / 4; ++i) {
        float4 a = sg4[i];
        float4 b = lg4[i];
        s_arr[4*i+0] = a.x; s_arr[4*i+1] = a.y; s_arr[4*i+2] = a.z; s_arr[4*i+3] = a.w;
        l_arr[4*i+0] = b.x; l_arr[4*i+1] = b.y; l_arr[4*i+2] = b.z; l_arr[4*i+3] = b.w;
    }

    float cur[CH * NOPS];
    {
        const f4v* v0 = reinterpret_cast<const f4v*>(op);
#pragma unroll
        for (int i = 0; i < 10; ++i) {          // chunk 0 = words 0..39
            f4v t = v0[i];
            cur[4*i+0] = t[0]; cur[4*i+1] = t[1];
            cur[4*i+2] = t[2]; cur[4*i+3] = t[3];
        }
    }

    // Pin the 64 stack values + 40 chunk-0 probs into live VGPRs.
#pragma unroll
    for (int i = 0; i < N_STACK; ++i) { PIN(s_arr[i]); PIN(l_arr[i]); }
#pragma unroll
    for (int j = 0; j < CH * NOPS; ++j) PIN(cur[j]);

    // Suffix sum-of-squares of ORIGINAL logs, positions 0..30 (top excluded).
    float S = 0.0f;
#pragma unroll
    for (int i = 0; i < N_STACK - 1; ++i) S = fmaf(l_arr[i], l_arr[i], S);

    // Accumulator = top of stack.
    float as_ = s_arr[N_STACK - 1];
    float al  = l_arr[N_STACK - 1];

#pragma unroll
    for (int c = 0; c < NCH; ++c) {
        // Issue loads for chunk c+1 NOW (they complete under chunk-c compute).
        float nxt[CH * NOPS];
        if (c + 1 < NCH) {
            const int base = (c + 1) * CH * NOPS;          // 40, 80, 120
            const f4v* vn = reinterpret_cast<const f4v*>(op + base);
            if (c + 1 < NCH - 1) {
#pragma unroll
                for (int i = 0; i < 10; ++i) {             // full 40-word chunk
                    f4v t = vn[i];
                    nxt[4*i+0] = t[0]; nxt[4*i+1] = t[1];
                    nxt[4*i+2] = t[2]; nxt[4*i+3] = t[3];
                }
            } else {
#pragma unroll
                for (int i = 0; i < 8; ++i) {              // last chunk: 35 words
                    f4v t = vn[i];
                    nxt[4*i+0] = t[0]; nxt[4*i+1] = t[1];
                    nxt[4*i+2] = t[2]; nxt[4*i+3] = t[3];
                }
                nxt[32] = op[base + 32];
                nxt[33] = op[base + 33];
                nxt[34] = op[base + 34];
#pragma unroll
                for (int j = 35; j < CH * NOPS; ++j) nxt[j] = 0.0f;
            }
        }

#pragma unroll
        for (int j = 0; j < CH; ++j) {
            const int k = c * CH + j;
            if (k < DEPTH) {
                float ss = s_arr[N_STACK - 2 - k];   // sec (original input)
                float sl = l_arr[N_STACK - 2 - k];

                float p0 = cur[NOPS*j + 0];
                float p1 = cur[NOPS*j + 1];
                float p2 = cur[NOPS*j + 2];
                float p3 = cur[NOPS*j + 3];
                float p4 = cur[NOPS*j + 4];

                // ---- shared add/sub numeric core (sign-independent) ----
                float d = sl - al;
                float mx = fmaxf(sl, al);
                float lse = mx + __logf(1.0f + __expf(-fabsf(d)));   // logaddexp
                float l_same_c = clip_log(lse);

                bool bx = (sl >= al);                 // bigger_is_x
                float big    = bx ? sl : al;
                float small_ = bx ? al : sl;
                float delta = fminf(fmaxf(small_ - big, -LOG_LIMF), -0.001f);
                float diff = __logf(1.0f - __expf(delta));           // log1p(-exp(delta))
                bool zres = (small_ == big);
                float nlog = zres ? 0.0f : (big + diff);

                // ---- add / sub branch combines ----
                float s_add, l_add, s_sub, l_sub;
                add_ls(ss, sl,  as_, al, l_same_c, nlog, zres, bx, s_add, l_add);
                add_ls(ss, sl, -as_, al, l_same_c, nlog, zres, bx, s_sub, l_sub);

                // ---- mul / div ----
                float sm   = ss * as_;
                float lmul = clip_log(sl + al);
                float ldiv = clip_log(sl - al);

                // ---- soft mix over [add, sub, mul, div, identity(sec)] ----
                float rs = p0 * s_add + p1 * s_sub + (p2 + p3) * sm + p4 * ss;
                float rl = p0 * l_add + p1 * l_sub + p2 * lmul + p3 * ldiv + p4 * sl;

                // ---- RMS rescale: slice = original logs 0..30-k ++ rl (cs = 32-k)
                const float inv_cs = 1.0f / (float)(N_STACK - k);    // compile-time
                float ms = fmaf(rl, rl, S) * inv_cs + 1e-6f;
                float scale = fminf(10.0f * __builtin_amdgcn_rsqf(ms), 1.0f);
                rl = rl * scale;

                // retire original element 30-k from the suffix sum
                S = fmaf(-sl, sl, S);

                as_ = rs;
                al  = rl;
            }
        }

        // Pin chunk c+1 AFTER chunk-c compute: the waitcnt lands here, behind
        // ~8 steps (~1000 cyc) of ALU work, then roll buffers (free renaming).
        if (c + 1 < NCH) {
#pragma unroll
            for (int j = 0; j < CH * NOPS; ++j) { PIN(nxt[j]); cur[j] = nxt[j]; }
        }
    }

    // Output: (2, B, T) flattened — [0..n) = sign, [n..2n) = log
    out[id]     = as_;
    out[n + id] = al;
}

extern "C" void kernel_launch(void* const* d_in, const int* in_sizes, int n_in,
                              void* d_out, int out_size, void* d_ws, size_t ws_size,
                              hipStream_t stream) {
    const float* sgn  = (const float*)d_in[0];
    const float* logm = (const float*)d_in[1];
    const float* ops  = (const float*)d_in[2];
    float* out = (float*)d_out;

    int n = in_sizes[0] / N_STACK;   // B*T = 131072
    int blocks = (n + BLOCK - 1) / BLOCK;
    stack_fold_kernel<<<blocks, BLOCK, 0, stream>>>(sgn, logm, ops, out, n);
}